// Round 10
// baseline (5112.116 us; speedup 1.0000x reference)
//
#include <hip/hip_runtime.h>
#include <stdint.h>

// SGL/LightGCN 3-layer propagation on MI355X (gfx950).
// ego=[200000,64] f32; 4M COO edges; per layer y[row] += val * x[col].
//
// v7: g-major streaming bin + LDS-staged deep-unrolled bucket SpMM.
//  Build: per-wg (g,b) histogram -> g-major exclusive scan -> each writer-wg
//  g streams its edges into ONE contiguous 250KB region (grouped by bucket
//  inside) => no cross-wg cache-line sharing => no line bouncing (v6's bin
//  failure: 400K tiny segments shared nearly every line across wgs).
//  A small kernel transposes the (start,len) table to b-major tseg[b][g].
//  SpMM: one wg per 64-row bucket; stage the bucket's <=1536 edges into LDS
//  (removes the bcv->x serial dependency hop), then wave-per-edge (lane=dim,
//  2-way LDS banks = free) with 8 independent 256B gathers in flight per
//  wave (2KB, 8x v6's MLP, which measured 1384us latency-starved).
//  Fused acc epilogue; zero f32 global atomics.
//
// ws: A 51.2 | B 51.2 (gh/gbase alias during build) | bcv 32 | tseg 3.2 MB.

constexpr int N_USER = 100000;
constexpr int NN     = 200000;            // N_NODES
constexpr int NE     = 4000000;           // N_EDGES
constexpr int EMB    = 64;
constexpr int RPB    = 64;                // rows per bucket
constexpr int NB     = NN / RPB;          // 3125 buckets
constexpr int COLB   = 18;                // col bits (200000 < 2^18)
constexpr int CMASK  = (1 << COLB) - 1;
constexpr int NWG    = 128;               // binning writer groups
constexpr int EPW    = NE / NWG;          // 31250 edges per writer group
constexpr int SCN    = NB * NWG;          // 400000 table entries
constexpr int CAP    = 1536;              // LDS edge-stage capacity (mean 1280)

// ---------------------------------------------------------------- init
__global__ __launch_bounds__(256) void init_kernel(
    const float4* __restrict__ user, const float4* __restrict__ item,
    float4* __restrict__ A, float4* __restrict__ acc)
{
    const int64_t half  = (int64_t)N_USER * EMB / 4;
    const int64_t total = (int64_t)NN * EMB / 4;
    for (int64_t i = blockIdx.x * (int64_t)blockDim.x + threadIdx.x; i < total;
         i += (int64_t)gridDim.x * blockDim.x) {
        const float4 v = (i < half) ? user[i] : item[i - half];
        A[i] = v;
        acc[i] = v;
    }
}

// ---------------------------------------------------------------- ghist:
// gh[g*NB + b] = #edges of writer-group g landing in bucket b  (g-major)
__global__ __launch_bounds__(1024) void ghist_kernel(
    const int* __restrict__ rows, int* __restrict__ gh)
{
    __shared__ int lh[NB];
    const int g = blockIdx.x, t = threadIdx.x;
    for (int i = t; i < NB; i += 1024) lh[i] = 0;
    __syncthreads();
    const int lo = g * EPW, hi = lo + EPW;
    for (int e = lo + t; e < hi; e += 1024)
        atomicAdd(&lh[rows[e] >> 6], 1);
    __syncthreads();
    for (int i = t; i < NB; i += 1024)
        gh[(int64_t)g * NB + i] = lh[i];          // contiguous per wg
}

// ---------------------------------------------------------------- scan:
// gbase = exclusive scan of gh (g-major); gbase[SCN] = NE sentinel.
__global__ __launch_bounds__(1024) void scan_kernel(
    const int* __restrict__ gh, int* __restrict__ gbase)
{
    __shared__ int sums[1024];
    const int t = threadIdx.x;
    constexpr int CH = (SCN + 1023) / 1024;       // 391
    const int start = t * CH;
    const int end   = (start + CH < SCN) ? start + CH : SCN;

    int s = 0;
    for (int i = start; i < end; ++i) s += gh[i];
    sums[t] = s;
    __syncthreads();
    for (int off = 1; off < 1024; off <<= 1) {
        const int x = sums[t];
        const int y = (t >= off) ? sums[t - off] : 0;
        __syncthreads();
        sums[t] = x + y;
        __syncthreads();
    }
    int run = (t == 0) ? 0 : sums[t - 1];
    for (int i = start; i < end; ++i) {
        gbase[i] = run;
        run += gh[i];
    }
    if (t == 0) gbase[SCN] = NE;
}

// ---------------------------------------------------------------- tseg:
// b-major descriptor table: tseg[b*NWG+g] = {start, len} of segment (g,b).
__global__ __launch_bounds__(256) void tseg_kernel(
    const int* __restrict__ gbase, int2* __restrict__ tseg)
{
    const int o = blockIdx.x * blockDim.x + threadIdx.x;
    if (o >= SCN) return;
    const int g = o & (NWG - 1);
    const int b = o >> 7;                          // NWG = 128
    const int i = g * NB + b;
    const int s0 = gbase[i];
    const int s1 = gbase[i + 1];                   // g-major: (g,b+1) or next region
    tseg[o] = make_int2(s0, s1 - s0);
}

// ---------------------------------------------------------------- bin:
// wg g streams its edges into its contiguous region, bucket-grouped inside.
__global__ __launch_bounds__(1024) void bin_kernel(
    const int* __restrict__ rows, const int* __restrict__ cols,
    const int* __restrict__ vals_bits, const int* __restrict__ gbase,
    int2* __restrict__ bcv)
{
    __shared__ int lcur[NB];
    const int g = blockIdx.x, t = threadIdx.x;
    for (int i = t; i < NB; i += 1024)
        lcur[i] = gbase[(int64_t)g * NB + i];      // contiguous load
    __syncthreads();
    const int lo = g * EPW, hi = lo + EPW;
    for (int e = lo + t; e < hi; e += 1024) {
        const int r = rows[e];
        const int p = atomicAdd(&lcur[r >> 6], 1);
        bcv[p] = make_int2(((r & 63) << COLB) | cols[e], vals_bits[e]);
    }
}

// ---------------------------------------------------------------- spmm:
// one wg per bucket: stage edges to LDS, 8-deep unrolled gathers into a
// 16KB LDS tile (wave-per-edge, lane = dim), fused acc epilogue.
template<bool FINAL>
__global__ __launch_bounds__(256) void spmm_bucket_kernel(
    const int2* __restrict__ tseg, const int2* __restrict__ bcv,
    const float* __restrict__ x, float4* __restrict__ y4,
    float4* __restrict__ acc4)
{
    __shared__ float tile[RPB * EMB];              // 16 KB
    __shared__ int2  estage[CAP];                  // 12 KB
    __shared__ int   sstart[NWG], slen[NWG], soff[NWG];
    float4* t4 = (float4*)tile;
    const int b = blockIdx.x, t = threadIdx.x;

    for (int i = t; i < RPB * EMB / 4; i += 256)
        t4[i] = make_float4(0.f, 0.f, 0.f, 0.f);
    if (t < NWG) {
        const int2 sg = tseg[b * NWG + t];
        sstart[t] = sg.x;
        slen[t]   = sg.y;
        soff[t]   = sg.y;
    }
    __syncthreads();
    // inclusive scan of the 128 segment lengths
    for (int off = 1; off < NWG; off <<= 1) {
        int v = 0, u = 0;
        if (t < NWG) { v = soff[t]; if (t >= off) u = soff[t - off]; }
        __syncthreads();
        if (t < NWG) soff[t] = v + u;
        __syncthreads();
    }
    const int M = soff[NWG - 1];                   // bucket edge count

    const int lane = t & 63, wv = t >> 6;

    if (M <= CAP) {
        // ---- stage: 2 threads per segment copy into packed LDS ----
        {
            const int g = t >> 1;
            const int dst = soff[g] - slen[g];
            const int src = sstart[g];
            const int len = slen[g];
            for (int i = (t & 1); i < len; i += 2)
                estage[dst + i] = bcv[src + i];
        }
        __syncthreads();
        // ---- process: 8 independent gathers in flight per wave ----
        int i = wv;
        for (; i + 28 < M; i += 32) {
            int2 c[8];
            float xv[8];
            #pragma unroll
            for (int k = 0; k < 8; ++k) c[k] = estage[i + 4 * k];
            #pragma unroll
            for (int k = 0; k < 8; ++k)
                xv[k] = x[(int64_t)(c[k].x & CMASK) * EMB + lane];
            #pragma unroll
            for (int k = 0; k < 8; ++k)
                atomicAdd(&tile[(((unsigned)c[k].x) >> COLB) * EMB + lane],
                          __builtin_bit_cast(float, c[k].y) * xv[k]);
        }
        for (; i < M; i += 4) {                    // tail
            const int2 c = estage[i];
            const float xv = x[(int64_t)(c.x & CMASK) * EMB + lane];
            atomicAdd(&tile[(((unsigned)c.x) >> COLB) * EMB + lane],
                      __builtin_bit_cast(float, c.y) * xv);
        }
    } else {
        // ---- fallback (never for this input): direct from global ----
        for (int g = wv; g < NWG; g += 4) {
            const int s0 = sstart[g], sl = slen[g];
            for (int i = 0; i < sl; ++i) {
                const int2 c = bcv[s0 + i];
                const float xv = x[(int64_t)(c.x & CMASK) * EMB + lane];
                atomicAdd(&tile[(((unsigned)c.x) >> COLB) * EMB + lane],
                          __builtin_bit_cast(float, c.y) * xv);
            }
        }
    }
    __syncthreads();

    for (int i = t; i < RPB * EMB / 4; i += 256) { // coalesced epilogue
        const float4 s = t4[i];
        const int64_t idx = (int64_t)b * (RPB * EMB / 4) + i;
        float4 a = acc4[idx];
        if constexpr (FINAL) {
            a.x = (a.x + s.x) * 0.25f; a.y = (a.y + s.y) * 0.25f;
            a.z = (a.z + s.z) * 0.25f; a.w = (a.w + s.w) * 0.25f;
            acc4[idx] = a;
        } else {
            y4[idx] = s;
            a.x += s.x; a.y += s.y; a.z += s.z; a.w += s.w;
            acc4[idx] = a;
        }
    }
}

extern "C" void kernel_launch(void* const* d_in, const int* in_sizes, int n_in,
                              void* d_out, int out_size, void* d_ws, size_t ws_size,
                              hipStream_t stream)
{
    const float* user = (const float*)d_in[0];
    const float* item = (const float*)d_in[1];
    const int*   rows = (const int*)d_in[2];
    const int*   cols = (const int*)d_in[3];
    const int*   vals = (const int*)d_in[4];   // f32 bits

    float* acc = (float*)d_out;                // [NN, EMB]

    // ---- workspace carve-up (~137.6MB) ----
    char* ws = (char*)d_ws;
    const size_t VEC_B = (size_t)NN * EMB * sizeof(float);   // 51.2 MB
    float* A     = (float*)(ws);
    float* B     = (float*)(ws + VEC_B);
    // build-only tables alias B (dead before spmm writes B):
    int*   gh    = (int*)  (ws + VEC_B);                     // 1.6 MB
    int*   gbase = (int*)  (ws + VEC_B + ((size_t)SCN * 4 + 255 & ~255ull));
    int2*  bcv   = (int2*) (ws + 2 * VEC_B);                 // 32 MB (persists)
    int2*  tseg  = (int2*) (ws + 2 * VEC_B + (size_t)NE * sizeof(int2)); // 3.2 MB

    const dim3 blk256(256), blk1k(1024);

    // ---- build ----
    init_kernel<<<1024, blk256, 0, stream>>>(
        (const float4*)user, (const float4*)item, (float4*)A, (float4*)acc);
    ghist_kernel<<<NWG, blk1k, 0, stream>>>(rows, gh);
    scan_kernel<<<1, blk1k, 0, stream>>>(gh, gbase);
    tseg_kernel<<<(SCN + 255) / 256, blk256, 0, stream>>>(gbase, tseg);
    bin_kernel<<<NWG, blk1k, 0, stream>>>(rows, cols, vals, gbase, bcv);

    // ---- 3 propagation layers (acc fused) ----
    spmm_bucket_kernel<false><<<NB, blk256, 0, stream>>>(tseg, bcv,
        A, (float4*)B, (float4*)acc);
    spmm_bucket_kernel<false><<<NB, blk256, 0, stream>>>(tseg, bcv,
        B, (float4*)A, (float4*)acc);
    spmm_bucket_kernel<true><<<NB, blk256, 0, stream>>>(tseg, bcv,
        A, (float4*)nullptr, (float4*)acc);
}

// Round 13
// 1239.460 us; speedup vs baseline: 4.1245x; 4.1245x over previous
//
#include <hip/hip_runtime.h>
#include <stdint.h>

// SGL/LightGCN 3-layer propagation on MI355X (gfx950).
// ego=[200000,64] f32; 4M COO edges; per layer y[row] += val * x[col].
//
// v8 (resubmit x2): v5's measured-good CSR + wave-per-row register-accum SpMM
// (v6/v7's LDS-tile spmm measured 1384/1420us -- per-edge LDS f32 atomics
// ~218cyc/edge -- reverted), with the build's measured pathology (global-
// cursor bin: 344us, 227MB line-amplified writes) replaced by g-major
// streaming bin: each of 64 writer-wgs owns ONE contiguous 500KB region
// (scan in (g,b)-major order) -> cross-wg line sharing only at 63 region
// boundaries. bucket_csr counting-sorts each 64-row bucket's 64 segments
// into row-sorted CSR (int LDS atomics only). Zero f32 atomics anywhere.
//
// ws: A 51.2 | B 51.2 (bcv 32MB aliases B during build) | csr_cv 32 |
//     rowptr 0.8 | gh 0.8 | gbase 0.8 | bucketBase small.  ~137MB.

constexpr int N_USER = 100000;
constexpr int NN     = 200000;            // N_NODES
constexpr int NE     = 4000000;           // N_EDGES
constexpr int EMB    = 64;
constexpr int RPB    = 64;                // rows per bucket
constexpr int NB     = NN / RPB;          // 3125 buckets
constexpr int COLB   = 18;                // col bits (200000 < 2^18)
constexpr int CMASK  = (1 << COLB) - 1;
constexpr int NWG    = 64;                // binning writer groups
constexpr int EPW    = NE / NWG;          // 62500 edges per writer group
constexpr int SCN    = NB * NWG;          // 200000 (g,b) cells

// ---------------------------------------------------------------- init
__global__ __launch_bounds__(256) void init_kernel(
    const float4* __restrict__ user, const float4* __restrict__ item,
    float4* __restrict__ A, float4* __restrict__ acc)
{
    const int64_t half  = (int64_t)N_USER * EMB / 4;
    const int64_t total = (int64_t)NN * EMB / 4;
    for (int64_t i = blockIdx.x * (int64_t)blockDim.x + threadIdx.x; i < total;
         i += (int64_t)gridDim.x * blockDim.x) {
        const float4 v = (i < half) ? user[i] : item[i - half];
        A[i] = v;
        acc[i] = v;
    }
}

// ---------------------------------------------------------------- ghist:
// gh[g*NB + b] = #edges of writer-group g landing in bucket b
__global__ __launch_bounds__(1024) void ghist_kernel(
    const int* __restrict__ rows, int* __restrict__ gh)
{
    __shared__ int lh[NB];
    const int g = blockIdx.x, t = threadIdx.x;
    for (int i = t; i < NB; i += 1024) lh[i] = 0;
    __syncthreads();
    const int lo = g * EPW, hi = lo + EPW;
    for (int e = lo + t; e < hi; e += 1024)
        atomicAdd(&lh[rows[e] >> 6], 1);
    __syncthreads();
    for (int i = t; i < NB; i += 1024)
        gh[(int64_t)g * NB + i] = lh[i];
}

// ---------------------------------------------------------------- scan_g:
// flat exclusive scan of gh in (g,b)-major order -> gbase[SCN+1]
__global__ __launch_bounds__(1024) void scan_g_kernel(
    const int* __restrict__ gh, int* __restrict__ gbase)
{
    __shared__ int sums[1024];
    const int t = threadIdx.x;
    constexpr int CH = (SCN + 1023) / 1024;            // 196
    const int start = t * CH;
    const int end   = (start + CH < SCN) ? start + CH : SCN;

    int s = 0;
    for (int i = start; i < end; ++i) s += gh[i];
    sums[t] = s;
    __syncthreads();
    for (int off = 1; off < 1024; off <<= 1) {
        const int x = sums[t];
        const int y = (t >= off) ? sums[t - off] : 0;
        __syncthreads();
        sums[t] = x + y;
        __syncthreads();
    }
    int run = (t == 0) ? 0 : sums[t - 1];
    for (int i = start; i < end; ++i) {
        gbase[i] = run;
        run += gh[i];
    }
    if (t == 0) gbase[SCN] = NE;
}

// ---------------------------------------------------------------- scan_b:
// bucketBase[b] = exclusive scan of cnt[b] = sum_g gh[g*NB+b]
__global__ __launch_bounds__(1024) void scan_b_kernel(
    const int* __restrict__ gh, int* __restrict__ bucketBase,
    int* __restrict__ rowptr)
{
    __shared__ int sums[1024];
    const int t = threadIdx.x;
    constexpr int CH = (NB + 1023) / 1024;             // 4
    const int start = t * CH;
    const int end   = (start + CH < NB) ? start + CH : NB;

    int cnt[CH];
    int s = 0;
    for (int i = start; i < end; ++i) {
        int c = 0;
        for (int g = 0; g < NWG; ++g) c += gh[(int64_t)g * NB + i];
        cnt[i - start] = c;
        s += c;
    }
    sums[t] = s;
    __syncthreads();
    for (int off = 1; off < 1024; off <<= 1) {
        const int x = sums[t];
        const int y = (t >= off) ? sums[t - off] : 0;
        __syncthreads();
        sums[t] = x + y;
        __syncthreads();
    }
    int run = (t == 0) ? 0 : sums[t - 1];
    for (int i = start; i < end; ++i) {
        bucketBase[i] = run;
        run += cnt[i - start];
    }
    if (t == 0) { bucketBase[NB] = NE; rowptr[NN] = NE; }
}

// ---------------------------------------------------------------- bin:
// wg g streams its edges into its contiguous 500KB region (bucket-grouped
// inside) as packed {lr<<COLB|col, val}. No cross-wg line sharing.
__global__ __launch_bounds__(1024) void bin_kernel(
    const int* __restrict__ rows, const int* __restrict__ cols,
    const int* __restrict__ vals_bits, const int* __restrict__ gbase,
    int2* __restrict__ bcv)
{
    __shared__ int lcur[NB];
    const int g = blockIdx.x, t = threadIdx.x;
    for (int i = t; i < NB; i += 1024)
        lcur[i] = gbase[(int64_t)g * NB + i];
    __syncthreads();
    const int lo = g * EPW, hi = lo + EPW;
    for (int e = lo + t; e < hi; e += 1024) {
        const int r = rows[e];
        const int p = atomicAdd(&lcur[r >> 6], 1);
        bcv[p] = make_int2(((r & 63) << COLB) | cols[e], vals_bits[e]);
    }
}

// ---------------------------------------------------------------- bucket_csr:
// per bucket: counting-sort its NWG segments into row-sorted CSR + rowptr.
__global__ __launch_bounds__(256) void bucket_csr_kernel(
    const int* __restrict__ gbase, const int* __restrict__ bucketBase,
    const int2* __restrict__ bcv, int2* __restrict__ csr_cv,
    int* __restrict__ rowptr)
{
    __shared__ int lcnt[RPB];
    __shared__ int lcur[RPB];
    __shared__ int sseg[NWG], slen[NWG];
    const int b  = blockIdx.x, t = threadIdx.x;
    const int bb = bucketBase[b];

    if (t < RPB) lcnt[t] = 0;
    if (t < NWG) {
        const int s0 = gbase[(int64_t)t * NB + b];
        sseg[t] = s0;
        slen[t] = gbase[(int64_t)t * NB + b + 1] - s0;  // flat scan -> valid
    }
    __syncthreads();

    // count: 4 threads per segment
    {
        const int g = t >> 2, sub = t & 3;
        const int s0 = sseg[g], sl = slen[g];
        for (int i = sub; i < sl; i += 4)
            atomicAdd(&lcnt[((unsigned)bcv[s0 + i].x) >> COLB], 1);
    }
    __syncthreads();
    if (t < 64) {                                      // wave 0 scans 64 counts
        const int v = lcnt[t];
        int s = v;
        #pragma unroll
        for (int off = 1; off < 64; off <<= 1) {
            const int u = __shfl_up(s, off, 64);
            if (t >= off) s += u;
        }
        const int excl = s - v;
        lcur[t] = excl;
        rowptr[b * RPB + t] = bb + excl;
    }
    __syncthreads();
    // place: 4 threads per segment
    {
        const int g = t >> 2, sub = t & 3;
        const int s0 = sseg[g], sl = slen[g];
        for (int i = sub; i < sl; i += 4) {
            const int2 pv = bcv[s0 + i];
            const int  lr = ((unsigned)pv.x) >> COLB;
            const int  p  = atomicAdd(&lcur[lr], 1);
            csr_cv[bb + p] = make_int2(pv.x & CMASK, pv.y);
        }
    }
}

// ---------------------------------------------------------------- spmm:
// wave per row, lane = dim, register accum, pair-unrolled; fused acc.
__global__ __launch_bounds__(256) void spmm_acc_kernel(
    const int* __restrict__ rowptr, const int2* __restrict__ csr_cv,
    const float* __restrict__ x, float* __restrict__ y, float* __restrict__ acc)
{
    const int lane = threadIdx.x & 63;
    const int wave = (int)((blockIdx.x * (int64_t)blockDim.x + threadIdx.x) >> 6);
    const int nw   = (int)(((int64_t)gridDim.x * blockDim.x) >> 6);

    for (int r = wave; r < NN; r += nw) {
        const int e0 = rowptr[r];
        const int e1 = rowptr[r + 1];
        float s0 = 0.f, s1 = 0.f;
        int e = e0;
        #pragma unroll 2
        for (; e + 1 < e1; e += 2) {
            const int2 cv0 = csr_cv[e];
            const int2 cv1 = csr_cv[e + 1];
            s0 = fmaf(__builtin_bit_cast(float, cv0.y),
                      x[(int64_t)cv0.x * EMB + lane], s0);
            s1 = fmaf(__builtin_bit_cast(float, cv1.y),
                      x[(int64_t)cv1.x * EMB + lane], s1);
        }
        if (e < e1) {
            const int2 cv = csr_cv[e];
            s0 = fmaf(__builtin_bit_cast(float, cv.y),
                      x[(int64_t)cv.x * EMB + lane], s0);
        }
        const float s = s0 + s1;
        const int64_t idx = (int64_t)r * EMB + lane;
        y[idx] = s;
        acc[idx] += s;
    }
}

// last layer: acc = (acc + s) / 4   (no y store)
__global__ __launch_bounds__(256) void spmm_final_kernel(
    const int* __restrict__ rowptr, const int2* __restrict__ csr_cv,
    const float* __restrict__ x, float* __restrict__ acc)
{
    const int lane = threadIdx.x & 63;
    const int wave = (int)((blockIdx.x * (int64_t)blockDim.x + threadIdx.x) >> 6);
    const int nw   = (int)(((int64_t)gridDim.x * blockDim.x) >> 6);

    for (int r = wave; r < NN; r += nw) {
        const int e0 = rowptr[r];
        const int e1 = rowptr[r + 1];
        float s0 = 0.f, s1 = 0.f;
        int e = e0;
        #pragma unroll 2
        for (; e + 1 < e1; e += 2) {
            const int2 cv0 = csr_cv[e];
            const int2 cv1 = csr_cv[e + 1];
            s0 = fmaf(__builtin_bit_cast(float, cv0.y),
                      x[(int64_t)cv0.x * EMB + lane], s0);
            s1 = fmaf(__builtin_bit_cast(float, cv1.y),
                      x[(int64_t)cv1.x * EMB + lane], s1);
        }
        if (e < e1) {
            const int2 cv = csr_cv[e];
            s0 = fmaf(__builtin_bit_cast(float, cv.y),
                      x[(int64_t)cv.x * EMB + lane], s0);
        }
        const int64_t idx = (int64_t)r * EMB + lane;
        acc[idx] = (acc[idx] + s0 + s1) * 0.25f;
    }
}

extern "C" void kernel_launch(void* const* d_in, const int* in_sizes, int n_in,
                              void* d_out, int out_size, void* d_ws, size_t ws_size,
                              hipStream_t stream)
{
    const float* user = (const float*)d_in[0];
    const float* item = (const float*)d_in[1];
    const int*   rows = (const int*)d_in[2];
    const int*   cols = (const int*)d_in[3];
    const int*   vals = (const int*)d_in[4];   // f32 bits

    float* acc = (float*)d_out;                // [NN, EMB]

    // ---- workspace carve-up (~137MB) ----
    char* ws = (char*)d_ws;
    const size_t VEC_B = (size_t)NN * EMB * sizeof(float);   // 51.2 MB
    float* A     = (float*)(ws);
    float* B     = (float*)(ws + VEC_B);
    int2*  bcv   = (int2*) (ws + VEC_B);       // 32 MB, aliases B during build
    char*  tail  = ws + 2 * VEC_B;
    int2*  csr_cv = (int2*)(tail);                   tail += (size_t)NE * sizeof(int2);   // 32 MB
    int*   rowptr = (int*)(tail);                    tail += ((size_t)(NN + 1) * 4 + 255) & ~255ull;
    int*   gh     = (int*)(tail);                    tail += ((size_t)SCN * 4 + 255) & ~255ull;
    int*   gbase  = (int*)(tail);                    tail += ((size_t)(SCN + 1) * 4 + 255) & ~255ull;
    int*   bucketBase = (int*)(tail);

    const dim3 blk256(256), blk1k(1024);
    const int spmmBlocks = 4096;               // 16K waves, ~12 rows/wave

    // ---- build ----
    init_kernel<<<1024, blk256, 0, stream>>>(
        (const float4*)user, (const float4*)item, (float4*)A, (float4*)acc);
    ghist_kernel<<<NWG, blk1k, 0, stream>>>(rows, gh);
    scan_g_kernel<<<1, blk1k, 0, stream>>>(gh, gbase);
    scan_b_kernel<<<1, blk1k, 0, stream>>>(gh, bucketBase, rowptr);
    bin_kernel<<<NWG, blk1k, 0, stream>>>(rows, cols, vals, gbase, bcv);
    bucket_csr_kernel<<<NB, blk256, 0, stream>>>(gbase, bucketBase, bcv,
                                                 csr_cv, rowptr);

    // ---- 3 propagation layers (acc fused) ----
    spmm_acc_kernel<<<spmmBlocks, blk256, 0, stream>>>(rowptr, csr_cv,
        A, B, acc);
    spmm_acc_kernel<<<spmmBlocks, blk256, 0, stream>>>(rowptr, csr_cv,
        B, A, acc);
    spmm_final_kernel<<<spmmBlocks, blk256, 0, stream>>>(rowptr, csr_cv,
        A, acc);
}